// Round 1
// baseline (145.315 us; speedup 1.0000x reference)
//
#include <hip/hip_runtime.h>
#include <math.h>

#define EPSV 1e-5f
#define KIN  19
#define HD   128
#define SROW 21   // 19 features padded to 21: gcd(21,32)=1 -> conflict-free writes

// One block per (b,t). blockDim = 256 = ND.
__global__ __launch_bounds__(256) void net_fused(
    const float* __restrict__ x0g, const float* __restrict__ xg,
    const int*   __restrict__ Ng,  const float* __restrict__ basisg,
    const float* __restrict__ vg,  const float* __restrict__ Pg,
    const float* __restrict__ W0,  const float* __restrict__ b0,
    const float* __restrict__ W1,  const float* __restrict__ b1,
    const float* __restrict__ W2,  const float* __restrict__ b2,
    float* __restrict__ out, int Tn, int NDn)
{
    __shared__ float S[256 * SROW];   // per-particle 19 features
    __shared__ float part[4][HD];     // per-wave pooled partials
    __shared__ float hvec[HD];        // pooled + logN
    __shared__ float h1vec[HD];       // layer-1 activations
    __shared__ float vred[4][3];      // v-mean wave partials

    const int bt   = blockIdx.x;
    const int b    = bt / Tn;
    const int tid  = threadIdx.x;
    const int lane = tid & 63;
    const int wave = tid >> 6;

    // ---- per-particle global loads (particle i = tid) ----
    const long pbase = ((long)bt * NDn + tid) * 3;
    const float xi0 = xg[pbase+0], xi1 = xg[pbase+1], xi2 = xg[pbase+2];
    const float vi0 = vg[pbase+0], vi1 = vg[pbase+1], vi2 = vg[pbase+2];

    // ---- v0 = mean_n v : wave shuffle reduce + LDS combine ----
    float s0 = vi0, s1 = vi1, s2 = vi2;
    #pragma unroll
    for (int off = 32; off > 0; off >>= 1) {
        s0 += __shfl_down(s0, off);
        s1 += __shfl_down(s1, off);
        s2 += __shfl_down(s2, off);
    }
    if (lane == 0) { vred[wave][0] = s0; vred[wave][1] = s1; vred[wave][2] = s2; }
    __syncthreads();
    const float inv_nd = 1.0f / (float)NDn;
    const float v00 = (vred[0][0]+vred[1][0]+vred[2][0]+vred[3][0]) * inv_nd;
    const float v01 = (vred[0][1]+vred[1][1]+vred[2][1]+vred[3][1]) * inv_nd;
    const float v02 = (vred[0][2]+vred[1][2]+vred[2][2]+vred[3][2]) * inv_nd;

    // ---- per-(b,t) scalars (computed redundantly; all cached loads) ----
    const float p0 = x0g[bt*3+0], p1 = x0g[bt*3+1], p2 = x0g[bt*3+2];
    float bas[3][3];
    #pragma unroll
    for (int k = 0; k < 3; ++k)
        #pragma unroll
        for (int c = 0; c < 3; ++c)
            bas[k][c] = basisg[(b*3 + k)*3 + c];

    const float x0n  = sqrtf(p0*p0 + p1*p1 + p2*p2) + EPSV;
    const float ix0n = 1.0f / x0n;
    const float x0u0 = p0*ix0n, x0u1 = p1*ix0n, x0u2 = p2*ix0n;

    const float v0n  = sqrtf(v00*v00 + v01*v01 + v02*v02) + EPSV;
    const float iv0n = 1.0f / v0n;
    const float v0u0 = v00*iv0n, v0u1 = v01*iv0n, v0u2 = v02*iv0n;

    const float logN = log1pf((float)Ng[bt]);

    // ---- per-particle features -> LDS ----
    {
        const float xn  = sqrtf(xi0*xi0 + xi1*xi1 + xi2*xi2) + EPSV;
        const float ixn = 1.0f / xn;
        const float xu0 = xi0*ixn, xu1 = xi1*ixn, xu2 = xi2*ixn;

        const float c0 = vi0 - v00, c1 = vi1 - v01, c2 = vi2 - v02;
        const float vn  = sqrtf(c0*c0 + c1*c1 + c2*c2) + EPSV;
        const float ivn = 1.0f / vn;
        const float vu0 = c0*ivn, vu1 = c1*ivn, vu2 = c2*ivn;

        float* Si = &S[tid * SROW];
        Si[0]  = xn;
        Si[1]  = xu0*bas[0][0] + xu1*bas[0][1] + xu2*bas[0][2];
        Si[2]  = xu0*bas[1][0] + xu1*bas[1][1] + xu2*bas[1][2];
        Si[3]  = xu0*bas[2][0] + xu1*bas[2][1] + xu2*bas[2][2];
        Si[4]  = logN;
        Si[5]  = x0n;
        Si[6]  = x0u0*bas[0][0] + x0u1*bas[0][1] + x0u2*bas[0][2];
        Si[7]  = x0u0*bas[1][0] + x0u1*bas[1][1] + x0u2*bas[1][2];
        Si[8]  = x0u0*bas[2][0] + x0u1*bas[2][1] + x0u2*bas[2][2];
        Si[9]  = v0n;
        Si[10] = v0u0*bas[0][0] + v0u1*bas[0][1] + v0u2*bas[0][2];
        Si[11] = v0u0*bas[1][0] + v0u1*bas[1][1] + v0u2*bas[1][2];
        Si[12] = v0u0*bas[2][0] + v0u1*bas[2][1] + v0u2*bas[2][2];
        Si[13] = x0u0*v0u0 + x0u1*v0u1 + x0u2*v0u2;
        Si[14] = vn;
        Si[15] = vu0*bas[0][0] + vu1*bas[0][1] + vu2*bas[0][2];
        Si[16] = vu0*bas[1][0] + vu1*bas[1][1] + vu2*bas[1][2];
        Si[17] = vu0*bas[2][0] + vu1*bas[2][1] + vu2*bas[2][2];
        Si[18] = xu0*vu0 + xu1*vu1 + xu2*vu2;
    }
    __syncthreads();

    // ---- layer 0 + leaky_relu + mean pool ----
    // thread -> (jg = tid&31: 4 output cols, pg = tid>>5: 32 particles)
    const int jg = tid & 31;
    const int pg = tid >> 5;
    const int j0 = jg * 4;

    float w[KIN][4];
    float bb[4];
    #pragma unroll
    for (int q = 0; q < 4; ++q) {
        const int j = j0 + q;
        bb[q] = (j < 127) ? b0[j] : 0.0f;
        #pragma unroll
        for (int k = 0; k < KIN; ++k)
            w[k][q] = (j < 127) ? W0[k*127 + j] : 0.0f;
    }

    float acc0 = 0.f, acc1 = 0.f, acc2 = 0.f, acc3 = 0.f;
    const int ip0 = pg * 32;
    for (int ii = 0; ii < 32; ++ii) {
        const float* f = &S[(ip0 + ii) * SROW];
        float d0 = bb[0], d1 = bb[1], d2 = bb[2], d3 = bb[3];
        #pragma unroll
        for (int k = 0; k < KIN; ++k) {
            const float fk = f[k];
            d0 += fk * w[k][0];
            d1 += fk * w[k][1];
            d2 += fk * w[k][2];
            d3 += fk * w[k][3];
        }
        acc0 += fmaxf(d0, 0.01f*d0);
        acc1 += fmaxf(d1, 0.01f*d1);
        acc2 += fmaxf(d2, 0.01f*d2);
        acc3 += fmaxf(d3, 0.01f*d3);
    }

    // combine particle-groups: pair within wave (pg, pg^1) ...
    acc0 += __shfl_xor(acc0, 32);
    acc1 += __shfl_xor(acc1, 32);
    acc2 += __shfl_xor(acc2, 32);
    acc3 += __shfl_xor(acc3, 32);
    // ... then across the 4 waves via LDS
    if (lane < 32) {
        part[wave][lane*4+0] = acc0;
        part[wave][lane*4+1] = acc1;
        part[wave][lane*4+2] = acc2;
        part[wave][lane*4+3] = acc3;
    }
    __syncthreads();
    if (tid < HD) {
        const float p = part[0][tid] + part[1][tid] + part[2][tid] + part[3][tid];
        hvec[tid] = (tid < 127) ? p * inv_nd : logN;
    }
    __syncthreads();

    // ---- layer 1 ----
    if (tid < HD) {
        float a = b1[tid];
        #pragma unroll 8
        for (int k = 0; k < HD; ++k) a += hvec[k] * W1[k*HD + tid];
        h1vec[tid] = fmaxf(a, 0.01f*a);
    }
    __syncthreads();

    // ---- layer 2 + output scale ----
    if (tid < HD) {
        float a = b2[tid];
        #pragma unroll 8
        for (int k = 0; k < HD; ++k) a += h1vec[k] * W2[k*HD + tid];
        out[(long)bt * HD + tid] = a / Pg[b];
    }
}

extern "C" void kernel_launch(void* const* d_in, const int* in_sizes, int n_in,
                              void* d_out, int out_size, void* d_ws, size_t ws_size,
                              hipStream_t stream) {
    const float* x0    = (const float*)d_in[0];
    const float* x     = (const float*)d_in[1];
    const int*   N     = (const int*)  d_in[2];
    const float* basis = (const float*)d_in[3];
    const float* v     = (const float*)d_in[4];
    const float* P200c = (const float*)d_in[5];
    const float* W0    = (const float*)d_in[6];
    const float* b0    = (const float*)d_in[7];
    const float* W1    = (const float*)d_in[8];
    const float* b1    = (const float*)d_in[9];
    const float* W2    = (const float*)d_in[10];
    const float* b2    = (const float*)d_in[11];
    float* out = (float*)d_out;

    const int B  = in_sizes[5];                 // P200c is [B]
    const int T  = in_sizes[2] / B;             // N is [B,T]
    const int ND = in_sizes[1] / (in_sizes[2] * 3);  // x is [B,T,ND,3]

    dim3 grid(B * T), block(256);
    hipLaunchKernelGGL(net_fused, grid, block, 0, stream,
                       x0, x, N, basis, v, P200c, W0, b0, W1, b1, W2, b2,
                       out, T, ND);
}

// Round 2
// 134.612 us; speedup vs baseline: 1.0795x; 1.0795x over previous
//
#include <hip/hip_runtime.h>
#include <math.h>

#define EPSV 1e-5f
#define KIN  19
#define HD   128
#define SROW 20   // 19 features + 1 pad -> 80B rows, 16B-aligned for ds_read_b128

// One block per (b,t). blockDim = 256 = ND.
// __launch_bounds__(256, 2): allow up to 256 VGPRs so the w[19][4] weight
// cache stays in registers (round 1: default bounds forced VGPR=64 -> scratch
// spill of the weight array -> 3x inner-loop cost).
__global__ __launch_bounds__(256, 2) void net_fused(
    const float* __restrict__ x0g, const float* __restrict__ xg,
    const int*   __restrict__ Ng,  const float* __restrict__ basisg,
    const float* __restrict__ vg,  const float* __restrict__ Pg,
    const float* __restrict__ W0,  const float* __restrict__ b0,
    const float* __restrict__ W1,  const float* __restrict__ b1,
    const float* __restrict__ W2,  const float* __restrict__ b2,
    float* __restrict__ out, int Tn, int NDn)
{
    __shared__ __align__(16) float S[256 * SROW];  // per-particle features
    __shared__ float part[4][HD];     // per-wave pooled partials
    __shared__ float hvec[HD];        // pooled + logN
    __shared__ float h1vec[HD];       // layer-1 activations
    __shared__ float tailred[2][HD];  // split-K partials for tail GEMVs
    __shared__ float vred[4][3];      // v-mean wave partials

    const int bt   = blockIdx.x;
    const int b    = bt / Tn;
    const int tid  = threadIdx.x;
    const int lane = tid & 63;
    const int wave = tid >> 6;

    // ---- per-particle global loads (particle i = tid) ----
    const long pbase = ((long)bt * NDn + tid) * 3;
    const float xi0 = xg[pbase+0], xi1 = xg[pbase+1], xi2 = xg[pbase+2];
    const float vi0 = vg[pbase+0], vi1 = vg[pbase+1], vi2 = vg[pbase+2];

    // ---- v0 = mean_n v : wave shuffle reduce + LDS combine ----
    float s0 = vi0, s1 = vi1, s2 = vi2;
    #pragma unroll
    for (int off = 32; off > 0; off >>= 1) {
        s0 += __shfl_down(s0, off);
        s1 += __shfl_down(s1, off);
        s2 += __shfl_down(s2, off);
    }
    if (lane == 0) { vred[wave][0] = s0; vred[wave][1] = s1; vred[wave][2] = s2; }
    __syncthreads();
    const float inv_nd = 1.0f / (float)NDn;
    const float v00 = (vred[0][0]+vred[1][0]+vred[2][0]+vred[3][0]) * inv_nd;
    const float v01 = (vred[0][1]+vred[1][1]+vred[2][1]+vred[3][1]) * inv_nd;
    const float v02 = (vred[0][2]+vred[1][2]+vred[2][2]+vred[3][2]) * inv_nd;

    // ---- per-(b,t) scalars (computed redundantly; all cached loads) ----
    const float p0 = x0g[bt*3+0], p1 = x0g[bt*3+1], p2 = x0g[bt*3+2];
    float bas[3][3];
    #pragma unroll
    for (int k = 0; k < 3; ++k)
        #pragma unroll
        for (int c = 0; c < 3; ++c)
            bas[k][c] = basisg[(b*3 + k)*3 + c];

    const float x0n  = sqrtf(p0*p0 + p1*p1 + p2*p2) + EPSV;
    const float ix0n = 1.0f / x0n;
    const float x0u0 = p0*ix0n, x0u1 = p1*ix0n, x0u2 = p2*ix0n;

    const float v0n  = sqrtf(v00*v00 + v01*v01 + v02*v02) + EPSV;
    const float iv0n = 1.0f / v0n;
    const float v0u0 = v00*iv0n, v0u1 = v01*iv0n, v0u2 = v02*iv0n;

    const float logN = log1pf((float)Ng[bt]);

    // ---- per-particle features -> LDS ----
    {
        const float xn  = sqrtf(xi0*xi0 + xi1*xi1 + xi2*xi2) + EPSV;
        const float ixn = 1.0f / xn;
        const float xu0 = xi0*ixn, xu1 = xi1*ixn, xu2 = xi2*ixn;

        const float c0 = vi0 - v00, c1 = vi1 - v01, c2 = vi2 - v02;
        const float vn  = sqrtf(c0*c0 + c1*c1 + c2*c2) + EPSV;
        const float ivn = 1.0f / vn;
        const float vu0 = c0*ivn, vu1 = c1*ivn, vu2 = c2*ivn;

        float* Si = &S[tid * SROW];
        Si[0]  = xn;
        Si[1]  = xu0*bas[0][0] + xu1*bas[0][1] + xu2*bas[0][2];
        Si[2]  = xu0*bas[1][0] + xu1*bas[1][1] + xu2*bas[1][2];
        Si[3]  = xu0*bas[2][0] + xu1*bas[2][1] + xu2*bas[2][2];
        Si[4]  = logN;
        Si[5]  = x0n;
        Si[6]  = x0u0*bas[0][0] + x0u1*bas[0][1] + x0u2*bas[0][2];
        Si[7]  = x0u0*bas[1][0] + x0u1*bas[1][1] + x0u2*bas[1][2];
        Si[8]  = x0u0*bas[2][0] + x0u1*bas[2][1] + x0u2*bas[2][2];
        Si[9]  = v0n;
        Si[10] = v0u0*bas[0][0] + v0u1*bas[0][1] + v0u2*bas[0][2];
        Si[11] = v0u0*bas[1][0] + v0u1*bas[1][1] + v0u2*bas[1][2];
        Si[12] = v0u0*bas[2][0] + v0u1*bas[2][1] + v0u2*bas[2][2];
        Si[13] = x0u0*v0u0 + x0u1*v0u1 + x0u2*v0u2;
        Si[14] = vn;
        Si[15] = vu0*bas[0][0] + vu1*bas[0][1] + vu2*bas[0][2];
        Si[16] = vu0*bas[1][0] + vu1*bas[1][1] + vu2*bas[1][2];
        Si[17] = vu0*bas[2][0] + vu1*bas[2][1] + vu2*bas[2][2];
        Si[18] = xu0*vu0 + xu1*vu1 + xu2*vu2;
        Si[19] = 0.0f;
    }
    __syncthreads();

    // ---- layer 0 + leaky_relu + mean pool ----
    // thread -> (jg = tid&31: 4 output cols, pg = tid>>5: 32 particles)
    const int jg = tid & 31;
    const int pg = tid >> 5;
    const int j0 = jg * 4;

    float w[KIN][4];
    float bb[4];
    #pragma unroll
    for (int q = 0; q < 4; ++q) {
        const int j = j0 + q;
        bb[q] = (j < 127) ? b0[j] : 0.0f;
        #pragma unroll
        for (int k = 0; k < KIN; ++k)
            w[k][q] = (j < 127) ? W0[k*127 + j] : 0.0f;
    }

    float acc0 = 0.f, acc1 = 0.f, acc2 = 0.f, acc3 = 0.f;
    const int ip0 = pg * 32;

    #define FMA4(fk, kk)                       \
        d0 = fmaf((fk), w[kk][0], d0);         \
        d1 = fmaf((fk), w[kk][1], d1);         \
        d2 = fmaf((fk), w[kk][2], d2);         \
        d3 = fmaf((fk), w[kk][3], d3);

    #pragma unroll 4
    for (int ii = 0; ii < 32; ++ii) {
        const float4* f4 = reinterpret_cast<const float4*>(&S[(ip0 + ii) * SROW]);
        const float4 fa = f4[0];
        const float4 fb = f4[1];
        const float4 fc = f4[2];
        const float4 fd = f4[3];
        const float4 fe = f4[4];
        float d0 = bb[0], d1 = bb[1], d2 = bb[2], d3 = bb[3];
        FMA4(fa.x, 0)  FMA4(fa.y, 1)  FMA4(fa.z, 2)  FMA4(fa.w, 3)
        FMA4(fb.x, 4)  FMA4(fb.y, 5)  FMA4(fb.z, 6)  FMA4(fb.w, 7)
        FMA4(fc.x, 8)  FMA4(fc.y, 9)  FMA4(fc.z, 10) FMA4(fc.w, 11)
        FMA4(fd.x, 12) FMA4(fd.y, 13) FMA4(fd.z, 14) FMA4(fd.w, 15)
        FMA4(fe.x, 16) FMA4(fe.y, 17) FMA4(fe.z, 18)
        acc0 += fmaxf(d0, 0.01f*d0);
        acc1 += fmaxf(d1, 0.01f*d1);
        acc2 += fmaxf(d2, 0.01f*d2);
        acc3 += fmaxf(d3, 0.01f*d3);
    }
    #undef FMA4

    // combine particle-groups: pair within wave (pg, pg^1) ...
    acc0 += __shfl_xor(acc0, 32);
    acc1 += __shfl_xor(acc1, 32);
    acc2 += __shfl_xor(acc2, 32);
    acc3 += __shfl_xor(acc3, 32);
    // ... then across the 4 waves via LDS
    if (lane < 32) {
        part[wave][lane*4+0] = acc0;
        part[wave][lane*4+1] = acc1;
        part[wave][lane*4+2] = acc2;
        part[wave][lane*4+3] = acc3;
    }
    __syncthreads();
    if (tid < HD) {
        const float p = part[0][tid] + part[1][tid] + part[2][tid] + part[3][tid];
        hvec[tid] = (tid < 127) ? p * inv_nd : logN;
    }
    __syncthreads();

    // ---- layer 1 (split-K over 2 thread groups) ----
    {
        const int j    = tid & 127;
        const int half = tid >> 7;
        const int kb   = half * 64;
        float a = 0.0f;
        #pragma unroll 8
        for (int k = 0; k < 64; ++k) a = fmaf(hvec[kb + k], W1[(kb + k)*HD + j], a);
        tailred[half][j] = a;
    }
    __syncthreads();
    if (tid < HD) {
        const float a = b1[tid] + tailred[0][tid] + tailred[1][tid];
        h1vec[tid] = fmaxf(a, 0.01f*a);
    }
    __syncthreads();

    // ---- layer 2 + output scale (split-K over 2 thread groups) ----
    {
        const int j    = tid & 127;
        const int half = tid >> 7;
        const int kb   = half * 64;
        float a = 0.0f;
        #pragma unroll 8
        for (int k = 0; k < 64; ++k) a = fmaf(h1vec[kb + k], W2[(kb + k)*HD + j], a);
        tailred[half][j] = a;
    }
    __syncthreads();
    if (tid < HD) {
        const float a = b2[tid] + tailred[0][tid] + tailred[1][tid];
        out[(long)bt * HD + tid] = a / Pg[b];
    }
}

extern "C" void kernel_launch(void* const* d_in, const int* in_sizes, int n_in,
                              void* d_out, int out_size, void* d_ws, size_t ws_size,
                              hipStream_t stream) {
    const float* x0    = (const float*)d_in[0];
    const float* x     = (const float*)d_in[1];
    const int*   N     = (const int*)  d_in[2];
    const float* basis = (const float*)d_in[3];
    const float* v     = (const float*)d_in[4];
    const float* P200c = (const float*)d_in[5];
    const float* W0    = (const float*)d_in[6];
    const float* b0    = (const float*)d_in[7];
    const float* W1    = (const float*)d_in[8];
    const float* b1    = (const float*)d_in[9];
    const float* W2    = (const float*)d_in[10];
    const float* b2    = (const float*)d_in[11];
    float* out = (float*)d_out;

    const int B  = in_sizes[5];                 // P200c is [B]
    const int T  = in_sizes[2] / B;             // N is [B,T]
    const int ND = in_sizes[1] / (in_sizes[2] * 3);  // x is [B,T,ND,3]

    dim3 grid(B * T), block(256);
    hipLaunchKernelGGL(net_fused, grid, block, 0, stream,
                       x0, x, N, basis, v, P200c, W0, b0, W1, b1, W2, b2,
                       out, T, ND);
}

// Round 5
// 118.953 us; speedup vs baseline: 1.2216x; 1.1316x over previous
//
#include <hip/hip_runtime.h>
#include <hip/hip_bf16.h>
#include <math.h>

#define EPSV 1e-5f
#define HD   128
#define AROW 40   // bf16 row stride: 80B, 16B-aligned, gcd(20,32)=4 -> 2-way alias (free)
#define WROW 40

typedef __attribute__((ext_vector_type(8))) short bf16x8;   // 8 bf16 = 4 VGPRs
typedef __attribute__((ext_vector_type(4))) float f32x4;

// One block per (b,t). blockDim = 256 = ND. 4 waves.
// Layer 0 split: 10 per-(b,t)-constant features (W0 rows 4..13) -> exact fp32
// per-column vector c[n] added pre-leaky; 9 particle-varying features ->
// compensated bf16 MFMA: A holds hi at k=0..8 and lo at k=16..24; B1 holds whi
// at both k-ranges (=> ahi*whi + alo*whi), B2 holds wlo at both (=> ahi*wlo +
// alo*wlo). Two MFMAs give the exact (ahi+alo)*(whi+wlo) product.
__global__ __launch_bounds__(256, 2) void net_fused(
    const float* __restrict__ x0g, const float* __restrict__ xg,
    const int*   __restrict__ Ng,  const float* __restrict__ basisg,
    const float* __restrict__ vg,  const float* __restrict__ Pg,
    const float* __restrict__ W0,  const float* __restrict__ b0,
    const float* __restrict__ W1,  const float* __restrict__ b1,
    const float* __restrict__ W2,  const float* __restrict__ b2,
    float* __restrict__ out, int Tn, int NDn)
{
    __shared__ __align__(16) __hip_bfloat16 SA[256 * AROW];   // varying feats hi|lo
    __shared__ __align__(16) __hip_bfloat16 Wt1[128 * WROW];  // whi | whi
    __shared__ __align__(16) __hip_bfloat16 Wt2[128 * WROW];  // wlo | wlo
    __shared__ float cvec[HD];        // exact constant-feature contribution
    __shared__ float part[4][HD];     // per-wave pooled partials
    __shared__ float hvec[HD];        // pooled + logN
    __shared__ float h1vec[HD];       // layer-1 activations
    __shared__ float tailred[2][HD];  // split-K partials for tail GEMVs
    __shared__ float vred[4][3];      // v-mean wave partials

    const int bt   = blockIdx.x;
    const int b    = bt / Tn;
    const int tid  = threadIdx.x;
    const int lane = tid & 63;
    const int wave = tid >> 6;

    // ---- per-particle global loads (particle i = tid) ----
    const long pbase = ((long)bt * NDn + tid) * 3;
    const float xi0 = xg[pbase+0], xi1 = xg[pbase+1], xi2 = xg[pbase+2];
    const float vi0 = vg[pbase+0], vi1 = vg[pbase+1], vi2 = vg[pbase+2];

    // ---- v0 = mean_n v : wave shuffle reduce + LDS combine ----
    float s0 = vi0, s1 = vi1, s2 = vi2;
    #pragma unroll
    for (int off = 32; off > 0; off >>= 1) {
        s0 += __shfl_down(s0, off);
        s1 += __shfl_down(s1, off);
        s2 += __shfl_down(s2, off);
    }
    if (lane == 0) { vred[wave][0] = s0; vred[wave][1] = s1; vred[wave][2] = s2; }

    // ---- stage Wt1/Wt2: varying-feature weight rows (W0 rows RV), hi|lo dup ----
    {
        const int RV[9] = {0, 1, 2, 3, 14, 15, 16, 17, 18};
        if (tid < 128) {
            const int n = tid;
            __hip_bfloat16* w1 = &Wt1[n * WROW];
            __hip_bfloat16* w2 = &Wt2[n * WROW];
            const __hip_bfloat16 z16 = __float2bfloat16(0.0f);
            #pragma unroll
            for (int kk = 0; kk < 9; ++kk) {
                const float wv = (n < 127) ? W0[RV[kk] * 127 + n] : 0.0f;
                const __hip_bfloat16 hi = __float2bfloat16(wv);
                const __hip_bfloat16 lo = __float2bfloat16(wv - __bfloat162float(hi));
                w1[kk] = hi;  w1[16 + kk] = hi;
                w2[kk] = lo;  w2[16 + kk] = lo;
            }
            #pragma unroll
            for (int kk = 9; kk < 16; ++kk) {
                w1[kk] = z16;  w1[kk + 16] = z16;   // 9..15 and 25..31
                w2[kk] = z16;  w2[kk + 16] = z16;
            }
        }
    }
    __syncthreads();

    const float inv_nd = 1.0f / (float)NDn;
    const float v00 = (vred[0][0]+vred[1][0]+vred[2][0]+vred[3][0]) * inv_nd;
    const float v01 = (vred[0][1]+vred[1][1]+vred[2][1]+vred[3][1]) * inv_nd;
    const float v02 = (vred[0][2]+vred[1][2]+vred[2][2]+vred[3][2]) * inv_nd;

    // ---- per-(b,t) scalars (computed redundantly; all cached loads) ----
    const float p0 = x0g[bt*3+0], p1 = x0g[bt*3+1], p2 = x0g[bt*3+2];
    float bas[3][3];
    #pragma unroll
    for (int k = 0; k < 3; ++k)
        #pragma unroll
        for (int c = 0; c < 3; ++c)
            bas[k][c] = basisg[(b*3 + k)*3 + c];

    const float x0n  = sqrtf(p0*p0 + p1*p1 + p2*p2) + EPSV;
    const float ix0n = 1.0f / x0n;
    const float x0u0 = p0*ix0n, x0u1 = p1*ix0n, x0u2 = p2*ix0n;

    const float v0n  = sqrtf(v00*v00 + v01*v01 + v02*v02) + EPSV;
    const float iv0n = 1.0f / v0n;
    const float v0u0 = v00*iv0n, v0u1 = v01*iv0n, v0u2 = v02*iv0n;

    const float logN = log1pf((float)Ng[bt]);

    // ---- exact fp32 constant-feature contribution c[n] (W0 rows 4..13) ----
    if (tid < 128) {
        float c = 0.0f;
        if (tid < 127) {
            float fc[10];
            fc[0] = logN;
            fc[1] = x0n;
            fc[2] = x0u0*bas[0][0] + x0u1*bas[0][1] + x0u2*bas[0][2];
            fc[3] = x0u0*bas[1][0] + x0u1*bas[1][1] + x0u2*bas[1][2];
            fc[4] = x0u0*bas[2][0] + x0u1*bas[2][1] + x0u2*bas[2][2];
            fc[5] = v0n;
            fc[6] = v0u0*bas[0][0] + v0u1*bas[0][1] + v0u2*bas[0][2];
            fc[7] = v0u0*bas[1][0] + v0u1*bas[1][1] + v0u2*bas[1][2];
            fc[8] = v0u0*bas[2][0] + v0u1*bas[2][1] + v0u2*bas[2][2];
            fc[9] = x0u0*v0u0 + x0u1*v0u1 + x0u2*v0u2;
            c = b0[tid];
            #pragma unroll
            for (int i = 0; i < 10; ++i)
                c = fmaf(fc[i], W0[(4 + i) * 127 + tid], c);
        }
        cvec[tid] = c;
    }

    // ---- per-particle varying features -> LDS (hi at k=0..8, lo at k=16..24) ----
    {
        const float xn  = sqrtf(xi0*xi0 + xi1*xi1 + xi2*xi2) + EPSV;
        const float ixn = 1.0f / xn;
        const float xu0 = xi0*ixn, xu1 = xi1*ixn, xu2 = xi2*ixn;

        const float c0 = vi0 - v00, c1 = vi1 - v01, c2 = vi2 - v02;
        const float vn  = sqrtf(c0*c0 + c1*c1 + c2*c2) + EPSV;
        const float ivn = 1.0f / vn;
        const float vu0 = c0*ivn, vu1 = c1*ivn, vu2 = c2*ivn;

        float f[9];
        f[0] = xn;                                            // W0 row 0
        f[1] = xu0*bas[0][0] + xu1*bas[0][1] + xu2*bas[0][2]; // row 1
        f[2] = xu0*bas[1][0] + xu1*bas[1][1] + xu2*bas[1][2]; // row 2
        f[3] = xu0*bas[2][0] + xu1*bas[2][1] + xu2*bas[2][2]; // row 3
        f[4] = vn;                                            // row 14
        f[5] = vu0*bas[0][0] + vu1*bas[0][1] + vu2*bas[0][2]; // row 15
        f[6] = vu0*bas[1][0] + vu1*bas[1][1] + vu2*bas[1][2]; // row 16
        f[7] = vu0*bas[2][0] + vu1*bas[2][1] + vu2*bas[2][2]; // row 17
        f[8] = xu0*vu0 + xu1*vu1 + xu2*vu2;                   // row 18

        __hip_bfloat16* Ar = &SA[tid * AROW];
        const __hip_bfloat16 z16 = __float2bfloat16(0.0f);
        #pragma unroll
        for (int kk = 0; kk < 9; ++kk) {
            const __hip_bfloat16 hi = __float2bfloat16(f[kk]);
            Ar[kk]      = hi;
            Ar[16 + kk] = __float2bfloat16(f[kk] - __bfloat162float(hi));
        }
        #pragma unroll
        for (int kk = 9; kk < 16; ++kk) {
            Ar[kk]      = z16;   // 9..15
            Ar[kk + 16] = z16;   // 25..31
        }
    }
    __syncthreads();

    // ---- layer 0 via MFMA: wave w owns particles [w*64, w*64+64) x 128 cols ----
    {
        const int quad = lane >> 4;
        const int lm   = lane & 15;

        bf16x8 bf1[8], bf2[8];
        float  cl[8];
        #pragma unroll
        for (int nt = 0; nt < 8; ++nt) {
            bf1[nt] = *reinterpret_cast<const bf16x8*>(&Wt1[(nt*16 + lm) * WROW + quad*8]);
            bf2[nt] = *reinterpret_cast<const bf16x8*>(&Wt2[(nt*16 + lm) * WROW + quad*8]);
            cl[nt]  = cvec[nt*16 + lm];
        }

        float pooled[8];
        #pragma unroll
        for (int nt = 0; nt < 8; ++nt) pooled[nt] = 0.0f;

        const f32x4 zero = {0.f, 0.f, 0.f, 0.f};
        #pragma unroll
        for (int mt = 0; mt < 4; ++mt) {
            const int particle = wave*64 + mt*16 + lm;
            const bf16x8 af = *reinterpret_cast<const bf16x8*>(&SA[particle * AROW + quad*8]);
            #pragma unroll
            for (int nt = 0; nt < 8; ++nt) {
                f32x4 acc = __builtin_amdgcn_mfma_f32_16x16x32_bf16(af, bf1[nt], zero, 0, 0, 0);
                acc = __builtin_amdgcn_mfma_f32_16x16x32_bf16(af, bf2[nt], acc, 0, 0, 0);
                float t = 0.0f;
                #pragma unroll
                for (int r = 0; r < 4; ++r) {
                    const float d = acc[r] + cl[nt];   // exact constant part
                    t += fmaxf(d, 0.01f*d);            // leaky_relu
                }
                pooled[nt] += t;
            }
        }
        // reduce across quads (rows) -> full col sums for this wave's 64 particles
        #pragma unroll
        for (int nt = 0; nt < 8; ++nt) {
            pooled[nt] += __shfl_xor(pooled[nt], 16);
            pooled[nt] += __shfl_xor(pooled[nt], 32);
        }
        if (lane < 16) {
            #pragma unroll
            for (int nt = 0; nt < 8; ++nt)
                part[wave][nt*16 + lane] = pooled[nt];
        }
    }
    __syncthreads();

    if (tid < HD) {
        const float p = part[0][tid] + part[1][tid] + part[2][tid] + part[3][tid];
        hvec[tid] = (tid < 127) ? p * inv_nd : logN;
    }
    __syncthreads();

    // ---- layer 1 (split-K over 2 thread groups) ----
    {
        const int j    = tid & 127;
        const int half = tid >> 7;
        const int kb   = half * 64;
        float a = 0.0f;
        #pragma unroll 8
        for (int k = 0; k < 64; ++k) a = fmaf(hvec[kb + k], W1[(kb + k)*HD + j], a);
        tailred[half][j] = a;
    }
    __syncthreads();
    if (tid < HD) {
        const float a = b1[tid] + tailred[0][tid] + tailred[1][tid];
        h1vec[tid] = fmaxf(a, 0.01f*a);
    }
    __syncthreads();

    // ---- layer 2 + output scale (split-K over 2 thread groups) ----
    {
        const int j    = tid & 127;
        const int half = tid >> 7;
        const int kb   = half * 64;
        float a = 0.0f;
        #pragma unroll 8
        for (int k = 0; k < 64; ++k) a = fmaf(h1vec[kb + k], W2[(kb + k)*HD + j], a);
        tailred[half][j] = a;
    }
    __syncthreads();
    if (tid < HD) {
        const float a = b2[tid] + tailred[0][tid] + tailred[1][tid];
        out[(long)bt * HD + tid] = a / Pg[b];
    }
}

extern "C" void kernel_launch(void* const* d_in, const int* in_sizes, int n_in,
                              void* d_out, int out_size, void* d_ws, size_t ws_size,
                              hipStream_t stream) {
    const float* x0    = (const float*)d_in[0];
    const float* x     = (const float*)d_in[1];
    const int*   N     = (const int*)  d_in[2];
    const float* basis = (const float*)d_in[3];
    const float* v     = (const float*)d_in[4];
    const float* P200c = (const float*)d_in[5];
    const float* W0    = (const float*)d_in[6];
    const float* b0    = (const float*)d_in[7];
    const float* W1    = (const float*)d_in[8];
    const float* b1    = (const float*)d_in[9];
    const float* W2    = (const float*)d_in[10];
    const float* b2    = (const float*)d_in[11];
    float* out = (float*)d_out;

    const int B  = in_sizes[5];                 // P200c is [B]
    const int T  = in_sizes[2] / B;             // N is [B,T]
    const int ND = in_sizes[1] / (in_sizes[2] * 3);  // x is [B,T,ND,3]

    dim3 grid(B * T), block(256);
    hipLaunchKernelGGL(net_fused, grid, block, 0, stream,
                       x0, x, N, basis, v, P200c, W0, b0, W1, b1, W2, b2,
                       out, T, ND);
}